// Round 1
// baseline (2335.541 us; speedup 1.0000x reference)
//
#include <hip/hip_runtime.h>

// EMA codebook update (VQ-VAE), MI355X fp32 baseline.
// N=32768 z-rows, K=8192 codes, D=256.

#define DECAY 0.99f
#define OMD 0.01f           // 1 - DECAY (same f32 as python 1.0-0.99)
#define EPS 1e-5f

constexpr int N = 32768, K = 8192, D = 256;
constexpr int BM = 128, BN = 128, DC = 32;
constexpr int NTHREADS = 512;

// d_out layout (floats, concatenated in reference return order)
constexpr long Q_OFF   = 0;                      // quantized  N*D
constexpr long IDX_OFF = (long)N * D;            // indices    N
constexpr long CB_OFF  = IDX_OFF + N;            // new_codebook K*D
constexpr long EMB_OFF = CB_OFF + (long)K * D;   // new_embedding_avg K*D
constexpr long CS_OFF  = EMB_OFF + (long)K * D;  // new_cluster_size K

// ws layout: [0..K) c2, [K] n accumulator

__global__ void init_kernel(const float* __restrict__ emb_avg,
                            const float* __restrict__ cs,
                            float* __restrict__ out) {
    int i = blockIdx.x * blockDim.x + threadIdx.x;   // over K*D/4
    const float4* e4 = (const float4*)emb_avg;
    float4* o4 = (float4*)(out + EMB_OFF);
    if (i < K * D / 4) {
        float4 v = e4[i];
        v.x *= DECAY; v.y *= DECAY; v.z *= DECAY; v.w *= DECAY;
        o4[i] = v;
    }
    if (i < K) out[CS_OFF + i] = cs[i] * DECAY;
}

__global__ void c2_kernel(const float* __restrict__ cb, float* __restrict__ ws) {
    int k = blockIdx.x;
    int lane = threadIdx.x;                 // 64 threads, one float4 each
    const float4* row = (const float4*)(cb + (long)k * D);
    float4 v = row[lane];
    float s = v.x * v.x + v.y * v.y + v.z * v.z + v.w * v.w;
    for (int off = 32; off; off >>= 1) s += __shfl_xor(s, off);
    if (lane == 0) ws[k] = s;
    if (k == 0 && lane == 0) ws[K] = 0.f;   // zero n-accum each call
}

__global__ __launch_bounds__(NTHREADS) void argmin_kernel(
        const float* __restrict__ z, const float* __restrict__ cb,
        const float* __restrict__ c2, float* __restrict__ out) {
    __shared__ float zT[DC][BM + 4];   // transposed, stride 132 (16B-aligned)
    __shared__ float cT[DC][BN + 4];
    __shared__ float c2s[BN];
    __shared__ int   idx_s[BM];

    const int tid = threadIdx.x;
    const int tx = tid & 31;           // 32 col-groups of 4
    const int ty = tid >> 5;           // 16 row-groups of 8
    const int rowBase = blockIdx.x * BM;
    const int rbase = ty * 8;
    const int cbase = tx * 4;

    float bestV[8]; int bestI[8];
#pragma unroll
    for (int r = 0; r < 8; ++r) { bestV[r] = 3.4e38f; bestI[r] = 0; }

    for (int kb = 0; kb < K; kb += BN) {
        __syncthreads();               // previous score-phase reads done
        if (tid < BN) c2s[tid] = c2[kb + tid];

        float acc[8][4];
#pragma unroll
        for (int r = 0; r < 8; ++r)
#pragma unroll
            for (int c = 0; c < 4; ++c) acc[r][c] = 0.f;

        for (int dc = 0; dc < D; dc += DC) {
            __syncthreads();           // previous compute reads done
#pragma unroll
            for (int s = 0; s < 2; ++s) {
                int f = tid + s * NTHREADS;   // 0..1023 float4 slots
                int row = f >> 3, dq = f & 7;
                float4 v = *(const float4*)(z + (long)(rowBase + row) * D + dc + dq * 4);
                zT[dq * 4 + 0][row] = v.x; zT[dq * 4 + 1][row] = v.y;
                zT[dq * 4 + 2][row] = v.z; zT[dq * 4 + 3][row] = v.w;
                float4 w = *(const float4*)(cb + (long)(kb + row) * D + dc + dq * 4);
                cT[dq * 4 + 0][row] = w.x; cT[dq * 4 + 1][row] = w.y;
                cT[dq * 4 + 2][row] = w.z; cT[dq * 4 + 3][row] = w.w;
            }
            __syncthreads();
#pragma unroll
            for (int d = 0; d < DC; ++d) {
                float a[8], b[4];
                *(float4*)&a[0] = *(const float4*)&zT[d][rbase];
                *(float4*)&a[4] = *(const float4*)&zT[d][rbase + 4];
                *(float4*)&b[0] = *(const float4*)&cT[d][cbase];
#pragma unroll
                for (int r = 0; r < 8; ++r)
#pragma unroll
                    for (int c = 0; c < 4; ++c)
                        acc[r][c] = fmaf(a[r], b[c], acc[r][c]);
            }
        }
        // score phase: dist-equivalent = c2 - 2*zc (z2 row-constant)
#pragma unroll
        for (int c = 0; c < 4; ++c) {
            float cc = c2s[cbase + c];
            int col = kb + cbase + c;
#pragma unroll
            for (int r = 0; r < 8; ++r) {
                float score = fmaf(-2.f, acc[r][c], cc);
                if (score < bestV[r]) { bestV[r] = score; bestI[r] = col; }
            }
        }
    }

    // reduce across the 32 lanes (tx) sharing the same rows; first-index ties
#pragma unroll
    for (int off = 16; off; off >>= 1) {
#pragma unroll
        for (int r = 0; r < 8; ++r) {
            float ov = __shfl_xor(bestV[r], off);
            int   oi = __shfl_xor(bestI[r], off);
            if (ov < bestV[r] || (ov == bestV[r] && oi < bestI[r])) {
                bestV[r] = ov; bestI[r] = oi;
            }
        }
    }
    if (tx == 0) {
#pragma unroll
        for (int r = 0; r < 8; ++r) idx_s[rbase + r] = bestI[r];
    }
    __syncthreads();

    // epilogue: indices, quantized gather, EMA scatter (atomics)
    int r = tid >> 2, seg = tid & 3;       // 128 rows x 4 segments of 64 floats
    int gRow = rowBase + r;
    int code = idx_s[r];
    if (seg == 0) {
        out[IDX_OFF + gRow] = (float)code;
        atomicAdd(&out[CS_OFF + code], OMD);
    }
    const float4* cbv = (const float4*)(cb + (long)code * D + seg * 64);
    const float4* zv  = (const float4*)(z + (long)gRow * D + seg * 64);
    float4* qv = (float4*)(out + Q_OFF + (long)gRow * D + seg * 64);
    float*  er = out + EMB_OFF + (long)code * D + seg * 64;
#pragma unroll 4
    for (int i = 0; i < 16; ++i) {
        float4 cv = cbv[i];
        qv[i] = cv;
        float4 zt = zv[i];
        atomicAdd(&er[i * 4 + 0], OMD * zt.x);
        atomicAdd(&er[i * 4 + 1], OMD * zt.y);
        atomicAdd(&er[i * 4 + 2], OMD * zt.z);
        atomicAdd(&er[i * 4 + 3], OMD * zt.w);
    }
}

__global__ void reduce_n(const float* __restrict__ out_cs, float* __restrict__ ws_n) {
    int i = blockIdx.x * 256 + threadIdx.x;    // K elements total
    float v = out_cs[i];
    for (int off = 32; off; off >>= 1) v += __shfl_xor(v, off);
    __shared__ float wsum[4];
    int lane = threadIdx.x & 63, w = threadIdx.x >> 6;
    if (lane == 0) wsum[w] = v;
    __syncthreads();
    if (threadIdx.x == 0) atomicAdd(ws_n, wsum[0] + wsum[1] + wsum[2] + wsum[3]);
}

__global__ void finalize_kernel(const float* __restrict__ ws, float* __restrict__ out) {
    int k = blockIdx.x, d = threadIdx.x;
    float n = ws[K];
    float ncs = out[CS_OFF + k];
    float smoothed = (ncs + EPS) / (n + (float)K * EPS) * n;
    out[CB_OFF + (long)k * D + d] = out[EMB_OFF + (long)k * D + d] / smoothed;
}

extern "C" void kernel_launch(void* const* d_in, const int* in_sizes, int n_in,
                              void* d_out, int out_size, void* d_ws, size_t ws_size,
                              hipStream_t stream) {
    const float* z   = (const float*)d_in[0];
    const float* cb  = (const float*)d_in[1];
    const float* emb = (const float*)d_in[2];
    const float* cs  = (const float*)d_in[3];
    float* out = (float*)d_out;
    float* ws  = (float*)d_ws;

    init_kernel<<<(K * D / 4 + 255) / 256, 256, 0, stream>>>(emb, cs, out);
    c2_kernel<<<K, 64, 0, stream>>>(cb, ws);
    argmin_kernel<<<N / BM, NTHREADS, 0, stream>>>(z, cb, ws, out);
    reduce_n<<<K / 256, 256, 0, stream>>>(out + CS_OFF, ws + K);
    finalize_kernel<<<K, 256, 0, stream>>>(ws, out);
}

// Round 2
// 2286.126 us; speedup vs baseline: 1.0216x; 1.0216x over previous
//
#include <hip/hip_runtime.h>

// EMA codebook update (VQ-VAE), MI355X fp32, K-split for occupancy.
// N=32768 z-rows, K=8192 codes, D=256.

#define DECAY 0.99f
#define OMD 0.01f           // 1 - DECAY
#define EPS 1e-5f

constexpr int N = 32768, K = 8192, D = 256;
constexpr int BM = 128, BN = 128, DC = 32;
constexpr int KSPLIT = 4;
constexpr int NTHREADS = 512;

// d_out layout (floats, concatenated in reference return order)
constexpr long Q_OFF   = 0;                      // quantized  N*D
constexpr long IDX_OFF = (long)N * D;            // indices    N
constexpr long CB_OFF  = IDX_OFF + N;            // new_codebook K*D
constexpr long EMB_OFF = CB_OFF + (long)K * D;   // new_embedding_avg K*D
constexpr long CS_OFF  = EMB_OFF + (long)K * D;  // new_cluster_size K

// ws layout: [0..N) u64 packed (score,idx) min; then K floats c2; then 1 float n-accum
__device__ inline unsigned long long packScore(float s, int idx) {
    unsigned u = __float_as_uint(s);
    u = (s >= 0.f) ? (u | 0x80000000u) : ~u;     // order-preserving float->uint
    return ((unsigned long long)u << 32) | (unsigned)idx;
}

__global__ void init_kernel(const float* __restrict__ emb_avg,
                            const float* __restrict__ cs,
                            float* __restrict__ out,
                            unsigned long long* __restrict__ wsmin) {
    int i = blockIdx.x * blockDim.x + threadIdx.x;   // over K*D/4
    const float4* e4 = (const float4*)emb_avg;
    float4* o4 = (float4*)(out + EMB_OFF);
    if (i < K * D / 4) {
        float4 v = e4[i];
        v.x *= DECAY; v.y *= DECAY; v.z *= DECAY; v.w *= DECAY;
        o4[i] = v;
    }
    if (i < K) out[CS_OFF + i] = cs[i] * DECAY;
    if (i < N) wsmin[i] = 0xFFFFFFFFFFFFFFFFull;
}

__global__ void c2_kernel(const float* __restrict__ cb, float* __restrict__ c2,
                          float* __restrict__ nacc) {
    int k = blockIdx.x;
    int lane = threadIdx.x;                 // 64 threads, one float4 each
    const float4* row = (const float4*)(cb + (long)k * D);
    float4 v = row[lane];
    float s = v.x * v.x + v.y * v.y + v.z * v.z + v.w * v.w;
    for (int off = 32; off; off >>= 1) s += __shfl_xor(s, off);
    if (lane == 0) c2[k] = s;
    if (k == 0 && lane == 0) *nacc = 0.f;
}

__global__ __launch_bounds__(NTHREADS) void argmin_kernel(
        const float* __restrict__ z, const float* __restrict__ cb,
        const float* __restrict__ c2, unsigned long long* __restrict__ wsmin) {
    __shared__ float zT[DC][BM + 4];   // transposed, stride 132 (16B-aligned)
    __shared__ float cT[DC][BN + 4];
    __shared__ float c2s[BN];

    const int tid = threadIdx.x;
    const int tx = tid & 31;           // 32 col-groups of 4
    const int ty = tid >> 5;           // 16 row-groups of 8
    const int rowBase = blockIdx.x * BM;
    const int kb0 = blockIdx.y * (K / KSPLIT);
    const int rbase = ty * 8;
    const int cbase = tx * 4;

    float bestV[8]; int bestI[8];
#pragma unroll
    for (int r = 0; r < 8; ++r) { bestV[r] = 3.4e38f; bestI[r] = 0; }

    for (int kt = 0; kt < K / KSPLIT; kt += BN) {
        const int kb = kb0 + kt;
        __syncthreads();               // previous score-phase reads done
        if (tid < BN) c2s[tid] = c2[kb + tid];

        float acc[8][4];
#pragma unroll
        for (int r = 0; r < 8; ++r)
#pragma unroll
            for (int c = 0; c < 4; ++c) acc[r][c] = 0.f;

        for (int dc = 0; dc < D; dc += DC) {
            __syncthreads();           // previous compute reads done
#pragma unroll
            for (int s = 0; s < 2; ++s) {
                int f = tid + s * NTHREADS;   // 0..1023 float4 slots
                int row = f >> 3, dq = f & 7;
                float4 v = *(const float4*)(z + (long)(rowBase + row) * D + dc + dq * 4);
                zT[dq * 4 + 0][row] = v.x; zT[dq * 4 + 1][row] = v.y;
                zT[dq * 4 + 2][row] = v.z; zT[dq * 4 + 3][row] = v.w;
                float4 w = *(const float4*)(cb + (long)(kb + row) * D + dc + dq * 4);
                cT[dq * 4 + 0][row] = w.x; cT[dq * 4 + 1][row] = w.y;
                cT[dq * 4 + 2][row] = w.z; cT[dq * 4 + 3][row] = w.w;
            }
            __syncthreads();
#pragma unroll
            for (int d = 0; d < DC; ++d) {
                float a[8], b[4];
                *(float4*)&a[0] = *(const float4*)&zT[d][rbase];
                *(float4*)&a[4] = *(const float4*)&zT[d][rbase + 4];
                *(float4*)&b[0] = *(const float4*)&cT[d][cbase];
#pragma unroll
                for (int r = 0; r < 8; ++r)
#pragma unroll
                    for (int c = 0; c < 4; ++c)
                        acc[r][c] = fmaf(a[r], b[c], acc[r][c]);
            }
        }
        // score phase: dist-equivalent = c2 - 2*zc (z2 row-constant)
#pragma unroll
        for (int c = 0; c < 4; ++c) {
            float cc = c2s[cbase + c];
            int col = kb + cbase + c;
#pragma unroll
            for (int r = 0; r < 8; ++r) {
                float score = fmaf(-2.f, acc[r][c], cc);
                if (score < bestV[r]) { bestV[r] = score; bestI[r] = col; }
            }
        }
    }

    // reduce across the 32 lanes (tx) sharing the same rows; first-index ties
#pragma unroll
    for (int off = 16; off; off >>= 1) {
#pragma unroll
        for (int r = 0; r < 8; ++r) {
            float ov = __shfl_xor(bestV[r], off);
            int   oi = __shfl_xor(bestI[r], off);
            if (ov < bestV[r] || (ov == bestV[r] && oi < bestI[r])) {
                bestV[r] = ov; bestI[r] = oi;
            }
        }
    }
    if (tx == 0) {
#pragma unroll
        for (int r = 0; r < 8; ++r)
            atomicMin(&wsmin[rowBase + rbase + r], packScore(bestV[r], bestI[r]));
    }
}

__global__ __launch_bounds__(NTHREADS) void epilogue_kernel(
        const float* __restrict__ z, const float* __restrict__ cb,
        const unsigned long long* __restrict__ wsmin, float* __restrict__ out) {
    int tid = threadIdx.x;
    int r = tid >> 2, seg = tid & 3;       // 128 rows x 4 segments of 64 floats
    int gRow = blockIdx.x * 128 + r;
    int code = (int)(wsmin[gRow] & 0xFFFFFFFFull);
    if (seg == 0) {
        out[IDX_OFF + gRow] = (float)code;
        atomicAdd(&out[CS_OFF + code], OMD);
    }
    const float4* cbv = (const float4*)(cb + (long)code * D + seg * 64);
    const float4* zv  = (const float4*)(z + (long)gRow * D + seg * 64);
    float4* qv = (float4*)(out + Q_OFF + (long)gRow * D + seg * 64);
    float*  er = out + EMB_OFF + (long)code * D + seg * 64;
#pragma unroll 4
    for (int i = 0; i < 16; ++i) {
        float4 cv = cbv[i];
        qv[i] = cv;
        float4 zt = zv[i];
        atomicAdd(&er[i * 4 + 0], OMD * zt.x);
        atomicAdd(&er[i * 4 + 1], OMD * zt.y);
        atomicAdd(&er[i * 4 + 2], OMD * zt.z);
        atomicAdd(&er[i * 4 + 3], OMD * zt.w);
    }
}

__global__ void reduce_n(const float* __restrict__ out_cs, float* __restrict__ nacc) {
    int i = blockIdx.x * 256 + threadIdx.x;    // K elements total
    float v = out_cs[i];
    for (int off = 32; off; off >>= 1) v += __shfl_xor(v, off);
    __shared__ float wsum[4];
    int lane = threadIdx.x & 63, w = threadIdx.x >> 6;
    if (lane == 0) wsum[w] = v;
    __syncthreads();
    if (threadIdx.x == 0) atomicAdd(nacc, wsum[0] + wsum[1] + wsum[2] + wsum[3]);
}

__global__ void finalize_kernel(const float* __restrict__ nacc, float* __restrict__ out) {
    int k = blockIdx.x, d = threadIdx.x;
    float n = *nacc;
    float ncs = out[CS_OFF + k];
    float smoothed = (ncs + EPS) / (n + (float)K * EPS) * n;
    out[CB_OFF + (long)k * D + d] = out[EMB_OFF + (long)k * D + d] / smoothed;
}

extern "C" void kernel_launch(void* const* d_in, const int* in_sizes, int n_in,
                              void* d_out, int out_size, void* d_ws, size_t ws_size,
                              hipStream_t stream) {
    const float* z   = (const float*)d_in[0];
    const float* cb  = (const float*)d_in[1];
    const float* emb = (const float*)d_in[2];
    const float* cs  = (const float*)d_in[3];
    float* out = (float*)d_out;
    unsigned long long* wsmin = (unsigned long long*)d_ws;
    float* c2 = (float*)d_ws + 2 * (long)N;        // after N u64
    float* nacc = c2 + K;

    init_kernel<<<(K * D / 4 + 255) / 256, 256, 0, stream>>>(emb, cs, out, wsmin);
    c2_kernel<<<K, 64, 0, stream>>>(cb, c2, nacc);
    dim3 agrid(N / BM, KSPLIT);
    argmin_kernel<<<agrid, NTHREADS, 0, stream>>>(z, cb, c2, wsmin);
    epilogue_kernel<<<N / 128, NTHREADS, 0, stream>>>(z, cb, wsmin, out);
    reduce_n<<<K / 256, 256, 0, stream>>>(out + CS_OFF, nacc);
    finalize_kernel<<<K, 256, 0, stream>>>(nacc, out);
}